// Round 6
// baseline (395.558 us; speedup 1.0000x reference)
//
#include <hip/hip_runtime.h>
#include <float.h>
#include <stdint.h>

constexpr int D_MODEL = 1024;
constexpr int DICT    = 16384;
constexpr int TOPK    = 8;
constexpr int NCAND   = 16;
constexpr int NTOK    = 4096;      // B*T
constexpr int NTILE   = 128;       // DICT / 128
constexpr long long COEFF_COUNT = (long long)NTOK * DICT;

typedef __attribute__((ext_vector_type(8))) __bf16 bf16x8;
typedef __attribute__((ext_vector_type(4))) float  floatx4;

__device__ __forceinline__ unsigned short f2bf(float f) {
    unsigned int u = __float_as_uint(f);
    u = u + 0x7fffu + ((u >> 16) & 1u);     // RNE
    return (unsigned short)(u >> 16);
}

__device__ __forceinline__ void async16(void* lds, const void* g) {
    __builtin_amdgcn_global_load_lds(
        (__attribute__((address_space(1))) void*)g,
        (__attribute__((address_space(3))) void*)lds, 16, 0, 0);
}

// ---------------------------------------------------------------------------
// fused fp32 -> bf16 convert for x and Wenc (one dispatch)
// ---------------------------------------------------------------------------
__global__ __launch_bounds__(256) void ssod_cvt2(const float4* __restrict__ xs, ushort4* __restrict__ xd, int nx4,
                                                 const float4* __restrict__ ws, ushort4* __restrict__ wd, int nw4) {
    const int i = blockIdx.x * 256 + threadIdx.x;
    if (i < nx4) {
        const float4 v = xs[i];
        ushort4 o; o.x = f2bf(v.x); o.y = f2bf(v.y); o.z = f2bf(v.z); o.w = f2bf(v.w);
        xd[i] = o;
    } else {
        const int j = i - nx4;
        if (j < nw4) {
            const float4 v = ws[j];
            ushort4 o; o.x = f2bf(v.x); o.y = f2bf(v.y); o.z = f2bf(v.z); o.w = f2bf(v.w);
            wd[j] = o;
        }
    }
}

// ---------------------------------------------------------------------------
// bf16 MFMA GEMM, BK=64, XOR-swizzled LDS (conflict-free frag reads), tile-max
// epilogue. Swizzle: LDS slot (row, jslot) holds logical 16B k-chunk
// jlog = jslot ^ (row & 7); applied on the global source address so the
// global_load_lds lane-contiguous LDS-dest requirement is untouched.
// Accumulation order identical to BK=32 version (bitwise-same coeffs).
// ---------------------------------------------------------------------------
__global__ __launch_bounds__(256) void ssod_gemm_bf16(const unsigned short* __restrict__ A,
                                                      const unsigned short* __restrict__ B,
                                                      unsigned short* __restrict__ C,
                                                      unsigned short* __restrict__ tmax) {
    __shared__ unsigned short As[128 * 64];
    __shared__ unsigned short Bs[128 * 64];
    __shared__ unsigned int rmax[128];

    const int tid  = threadIdx.x;
    const int wave = tid >> 6;
    const int lane = tid & 63;
    const int bn   = blockIdx.x;          // dict tile
    const int bm   = blockIdx.y;          // token tile
    const int wm   = wave >> 1;
    const int wn   = wave & 1;

    const unsigned short* Abase = A + (size_t)bm * 128 * D_MODEL;
    const unsigned short* Bbase = B + (size_t)bn * 128 * D_MODEL;

    floatx4 acc[4][4];
    #pragma unroll
    for (int i = 0; i < 4; ++i)
        #pragma unroll
        for (int j = 0; j < 4; ++j) acc[i][j] = floatx4{0.f, 0.f, 0.f, 0.f};

    const int fr = lane & 15;             // row within 16x16 frag
    const int kg = lane >> 4;             // k-group (8 elems each)

    for (int k0 = 0; k0 < D_MODEL; k0 += 64) {
        #pragma unroll
        for (int p = 0; p < 4; ++p) {
            const int s = wave * 64 + lane + p * 256;   // slot 0..1023
            const int r = s >> 3;                       // row 0..127
            const int jlog = (s & 7) ^ (r & 7);         // logical k-chunk
            async16(&As[s * 8], Abase + (size_t)r * D_MODEL + k0 + jlog * 8);
            async16(&Bs[s * 8], Bbase + (size_t)r * D_MODEL + k0 + jlog * 8);
        }
        __syncthreads();

        #pragma unroll
        for (int kk = 0; kk < 2; ++kk) {
            bf16x8 af[4], bfr[4];
            #pragma unroll
            for (int f = 0; f < 4; ++f) {
                const int ra = wm * 64 + f * 16 + fr;
                const int ja = (kk * 4 + kg) ^ (ra & 7);
                af[f] = *(const bf16x8*)&As[ra * 64 + ja * 8];
                const int rb = wn * 64 + f * 16 + fr;
                const int jb = (kk * 4 + kg) ^ (rb & 7);
                bfr[f] = *(const bf16x8*)&Bs[rb * 64 + jb * 8];
            }
            #pragma unroll
            for (int i = 0; i < 4; ++i)
                #pragma unroll
                for (int j = 0; j < 4; ++j)
                    acc[i][j] = __builtin_amdgcn_mfma_f32_16x16x32_bf16(af[i], bfr[j], acc[i][j], 0, 0, 0);
        }
        __syncthreads();
    }

    if (tid < 128) rmax[tid] = 0;

    // C/D layout: col = lane&15, row = (lane>>4)*4 + reg
    const int col = lane & 15;
    const int rq  = lane >> 4;
    unsigned int rowm[4][4];
    #pragma unroll
    for (int i = 0; i < 4; ++i)
        #pragma unroll
        for (int r = 0; r < 4; ++r) rowm[i][r] = 0;

    #pragma unroll
    for (int i = 0; i < 4; ++i) {
        const int row = bm * 128 + wm * 64 + i * 16 + rq * 4;
        #pragma unroll
        for (int j = 0; j < 4; ++j) {
            const int ccol = bn * 128 + wn * 64 + j * 16 + col;
            unsigned short* cp = C + (size_t)row * DICT + ccol;
            #pragma unroll
            for (int r = 0; r < 4; ++r) {
                const unsigned short bf = f2bf(acc[i][j][r]);
                cp[(size_t)r * DICT] = bf;
                rowm[i][r] = max(rowm[i][r], (unsigned int)(bf ^ 0x8000u));
            }
        }
    }
    __syncthreads();   // rmax init visible

    #pragma unroll
    for (int i = 0; i < 4; ++i)
        #pragma unroll
        for (int r = 0; r < 4; ++r) {
            unsigned int m = rowm[i][r];
            m = max(m, (unsigned int)__shfl_xor((int)m, 1, 64));
            m = max(m, (unsigned int)__shfl_xor((int)m, 2, 64));
            m = max(m, (unsigned int)__shfl_xor((int)m, 4, 64));
            m = max(m, (unsigned int)__shfl_xor((int)m, 8, 64));
            if ((lane & 15) == 0)
                atomicMax(&rmax[wm * 64 + i * 16 + rq * 4 + r], m);
        }
    __syncthreads();

    if (tid < 128)
        tmax[(size_t)(bm * 128 + tid) * NTILE + bn] = (unsigned short)rmax[tid];
}

// ---------------------------------------------------------------------------
// K1: exact bf16 top-16 per token, ONE WAVE per token (4 tokens/block), zero
// block barriers. tau = 16th-largest tile-max; gather qualifying tiles only;
// collect >= tau; 128-key bitonic. Per-wave LDS segments + wave lockstep.
// ---------------------------------------------------------------------------
__global__ __launch_bounds__(256) void ssod_select(const unsigned short* __restrict__ coeffs,
                                                   const unsigned short* __restrict__ tmax,
                                                   int* __restrict__ cand,
                                                   int tokBase) {
    const int tid  = threadIdx.x;
    const int lane = tid & 63;
    const int wave = tid >> 6;
    const int tl   = blockIdx.x * 4 + wave;     // chunk-local token
    const int t    = tokBase + tl;              // global token

    __shared__ int          tlistAll[4][128];
    __shared__ unsigned int keysAll[4][128];
    __shared__ int          cntAll[4][2];
    int*          tlist = tlistAll[wave];
    unsigned int* keys  = keysAll[wave];
    int*          cnts  = cntAll[wave];
    if (lane == 0) { cnts[0] = 0; cnts[1] = 0; }

    // ---- tau: 16th-largest of 128 tile maxes (2-reg bitonic, desc) ----
    const unsigned short* tmrow = tmax + (size_t)t * NTILE;
    const unsigned int u = ((const unsigned int*)tmrow)[lane];
    {
        unsigned int v0 = u & 0xFFFFu, v1 = u >> 16;
        for (int k = 2; k <= 128; k <<= 1) {
            for (int j = k >> 1; j >= 1; j >>= 1) {
                if (j == 64) {
                    const unsigned int a = max(v0, v1), b = min(v0, v1);
                    v0 = a; v1 = b;
                } else {
                    const unsigned int p0 = __shfl_xor(v0, j, 64);
                    const unsigned int p1 = __shfl_xor(v1, j, 64);
                    const bool tm0 = ((lane & j) == 0) ^ ((( lane      ) & k) != 0);
                    const bool tm1 = ((lane & j) == 0) ^ (((lane + 64) & k) != 0);
                    v0 = tm0 ? max(v0, p0) : min(v0, p0);
                    v1 = tm1 ? max(v1, p1) : min(v1, p1);
                }
            }
        }
        keys[0] = __shfl((int)v0, 15, 64);   // stash tau (reuse keys slot pre-collect)
    }
    const unsigned int tau = keys[0];

    // ---- qualifying tile list (each lane owns tiles 2*lane, 2*lane+1) ----
    if ((u & 0xFFFFu) >= tau) { const int p = atomicAdd(&cnts[0], 1); tlist[p] = 2 * lane; }
    if ((u >> 16)     >= tau) { const int p = atomicAdd(&cnts[0], 1); tlist[p] = 2 * lane + 1; }
    const int nq = cnts[0];

    // ---- collect elems >= tau from qualifying tiles ----
    const uint4* row4 = (const uint4*)(coeffs + (size_t)tl * DICT);
    for (int j = lane; j < nq * 16; j += 64) {
        const int tile = tlist[j >> 4];
        const int sub  = j & 15;
        const uint4 p = row4[tile * 16 + sub];
        const unsigned int w[4] = {p.x ^ 0x80008000u, p.y ^ 0x80008000u,
                                   p.z ^ 0x80008000u, p.w ^ 0x80008000u};
        const int base = tile * 128 + sub * 8;
        #pragma unroll
        for (int h = 0; h < 4; ++h) {
            const unsigned int lo = w[h] & 0xFFFFu, hi = w[h] >> 16;
            if (lo >= tau) {
                const int q = atomicAdd(&cnts[1], 1);
                if (q < 128) keys[q] = (lo << 16) | (unsigned)(16383 - (base + h * 2));
            }
            if (hi >= tau) {
                const int q = atomicAdd(&cnts[1], 1);
                if (q < 128) keys[q] = (hi << 16) | (unsigned)(16383 - (base + h * 2 + 1));
            }
        }
    }
    const int m = min(cnts[1], 128);
    for (int i = m + lane; i < 128; i += 64) keys[i] = 0;

    // ---- bitonic sort 128 keys desc (2-reg), emit top-16 indices ----
    {
        unsigned int v0 = keys[lane], v1 = keys[lane + 64];
        for (int k = 2; k <= 128; k <<= 1) {
            for (int j = k >> 1; j >= 1; j >>= 1) {
                if (j == 64) {
                    const unsigned int a = max(v0, v1), b = min(v0, v1);
                    v0 = a; v1 = b;
                } else {
                    const unsigned int p0 = __shfl_xor(v0, j, 64);
                    const unsigned int p1 = __shfl_xor(v1, j, 64);
                    const bool tm0 = ((lane & j) == 0) ^ ((( lane      ) & k) != 0);
                    const bool tm1 = ((lane & j) == 0) ^ (((lane + 64) & k) != 0);
                    v0 = tm0 ? max(v0, p0) : min(v0, p0);
                    v1 = tm1 ? max(v1, p1) : min(v1, p1);
                }
            }
        }
        if (lane < NCAND) cand[(size_t)t * NCAND + lane] = 16383 - (int)(v0 & 0xFFFFu);
    }
}

// ---------------------------------------------------------------------------
// K2: fp32 refine of 16 candidates + exact top-8 + fused offset.
// Each wave reads its own 4 cand indices from global and issues all 16 Wenc
// float4 gathers BEFORE the x-staging barrier (gathers overlap the chain).
// ---------------------------------------------------------------------------
__device__ __forceinline__ bool tk_better(float v1, int i1, float v2, int i2) {
    return (v1 > v2) || (v1 == v2 && i1 < i2);
}

__global__ __launch_bounds__(256) void ssod_refine(const int* __restrict__ cand,
                                                   const float* __restrict__ x,
                                                   const float* __restrict__ Wenc,
                                                   const float* __restrict__ Wdict,
                                                   float* __restrict__ outp,
                                                   float* __restrict__ tsum) {
    const int t    = blockIdx.x;
    const int tid  = threadIdx.x;
    const int lane = tid & 63;
    const int wave = tid >> 6;

    __shared__ float xs[D_MODEL];
    __shared__ int   cidx[NCAND];
    __shared__ float cval[NCAND];
    __shared__ float sval[TOPK];
    __shared__ int   sidx[TOPK];

    // per-wave candidate rows (global read; L2-hot) -> issue gathers early
    int myc[4];
    #pragma unroll
    for (int s = 0; s < 4; ++s) myc[s] = cand[(size_t)t * NCAND + s * 4 + wave];

    float4 wv[4][4];
    #pragma unroll
    for (int s = 0; s < 4; ++s) {
        const float4* wr4 = (const float4*)(Wenc + (size_t)myc[s] * D_MODEL);
        #pragma unroll
        for (int q = 0; q < 4; ++q) wv[s][q] = wr4[q * 64 + lane];
    }

    ((float4*)xs)[tid] = ((const float4*)(x + (size_t)t * D_MODEL))[tid];
    if (tid < NCAND) cidx[tid] = cand[(size_t)t * NCAND + tid];
    __syncthreads();

    const float4* xs4 = (const float4*)xs;
    float4 xv[4];
    #pragma unroll
    for (int q = 0; q < 4; ++q) xv[q] = xs4[q * 64 + lane];

    #pragma unroll
    for (int s = 0; s < 4; ++s) {
        float sum = 0.f;
        #pragma unroll
        for (int q = 0; q < 4; ++q)
            sum += xv[q].x * wv[s][q].x + xv[q].y * wv[s][q].y +
                   xv[q].z * wv[s][q].z + xv[q].w * wv[s][q].w;
        #pragma unroll
        for (int off = 32; off > 0; off >>= 1) sum += __shfl_down(sum, off, 64);
        if (lane == 0) cval[s * 4 + wave] = sum;
    }
    __syncthreads();

    // parallel rank-based exact top-8
    if (tid < NCAND) {
        const float v = cval[tid];
        const int  ix = cidx[tid];
        int rank = 0;
        #pragma unroll
        for (int j = 0; j < NCAND; ++j)
            rank += (j != tid) && tk_better(cval[j], cidx[j], v, ix);
        if (rank < TOPK) { sval[rank] = v; sidx[rank] = ix; }
    }
    __syncthreads();
    if (tid == 0) {
        float s = 0.f;
        #pragma unroll
        for (int k = 0; k < TOPK; ++k) s += fabsf(sval[k]);
        tsum[t] = s;
    }

    const int dd = tid * 4;
    float4 a = make_float4(0.f, 0.f, 0.f, 0.f);
    #pragma unroll
    for (int k = 0; k < TOPK; ++k) {
        const float4 r = *(const float4*)(Wdict + (size_t)sidx[k] * D_MODEL + dd);
        const float s = sval[k];
        a.x += s * r.x; a.y += s * r.y; a.z += s * r.z; a.w += s * r.w;
    }
    *(float4*)(outp + (size_t)t * D_MODEL + dd) = a;
}

// ---------------------------------------------------------------------------
// loss = sum(tsum) / (NTOK*DICT)
// ---------------------------------------------------------------------------
__global__ __launch_bounds__(256) void ssod_loss(const float* __restrict__ tsum,
                                                 float* __restrict__ out) {
    float s = 0.f;
    for (int i = threadIdx.x; i < NTOK; i += 256) s += tsum[i];
    #pragma unroll
    for (int off = 32; off > 0; off >>= 1) s += __shfl_down(s, off, 64);
    __shared__ float wsum[4];
    if ((threadIdx.x & 63) == 0) wsum[threadIdx.x >> 6] = s;
    __syncthreads();
    if (threadIdx.x == 0) {
        const float tot = wsum[0] + wsum[1] + wsum[2] + wsum[3];
        out[(size_t)NTOK * D_MODEL] = tot / (float)COEFF_COUNT;
    }
}

// ---------------------------------------------------------------------------
extern "C" void kernel_launch(void* const* d_in, const int* in_sizes, int n_in,
                              void* d_out, int out_size, void* d_ws, size_t ws_size,
                              hipStream_t stream) {
    const float* x     = (const float*)d_in[0];   // [4096,1024]
    const float* Wenc  = (const float*)d_in[1];   // [16384,1024]
    const float* Wdict = (const float*)d_in[2];   // [16384,1024]
    float* out = (float*)d_out;

    char* ws = (char*)d_ws;
    size_t off = 0;
    unsigned short* xbf  = (unsigned short*)(ws + off); off += (size_t)NTOK * D_MODEL * 2;  // 8 MB
    unsigned short* wbf  = (unsigned short*)(ws + off); off += (size_t)DICT * D_MODEL * 2;  // 33.6 MB
    unsigned short* tmax = (unsigned short*)(ws + off); off += (size_t)NTOK * NTILE * 2;    // 1 MB
    int*   cand = (int*)(ws + off);                     off += (size_t)NTOK * NCAND * 4;    // 256 KB
    float* tsum = (float*)(ws + off);                   off += (size_t)NTOK * 4;            // 16 KB
    unsigned short* coeffs = (unsigned short*)(ws + off);

    const size_t remain = (ws_size > off) ? (ws_size - off) : 0;
    int chunk = 512;
    if (remain >= (size_t)4096 * DICT * 2) chunk = 4096;
    else if (remain >= (size_t)2048 * DICT * 2) chunk = 2048;
    else if (remain >= (size_t)1024 * DICT * 2) chunk = 1024;

    const int nx4 = NTOK * D_MODEL / 4;
    const int nw4 = DICT * D_MODEL / 4;
    ssod_cvt2<<<(nx4 + nw4 + 255) / 256, 256, 0, stream>>>(
        (const float4*)x, (ushort4*)xbf, nx4, (const float4*)Wenc, (ushort4*)wbf, nw4);

    for (int tokBase = 0; tokBase < NTOK; tokBase += chunk) {
        dim3 g(DICT / 128, chunk / 128);
        ssod_gemm_bf16<<<g, 256, 0, stream>>>(xbf + (size_t)tokBase * D_MODEL, wbf, coeffs,
                                              tmax + (size_t)tokBase * NTILE);
        ssod_select<<<chunk / 4, 256, 0, stream>>>(coeffs, tmax, cand, tokBase);
    }
    ssod_refine<<<NTOK, 256, 0, stream>>>(cand, x, Wenc, Wdict, out, tsum);
    ssod_loss<<<1, 256, 0, stream>>>(tsum, out);
}